// Round 14
// baseline (583.975 us; speedup 1.0000x reference)
//
#include <hip/hip_runtime.h>
#include <stdint.h>

// out[b,s,o] = sum_i x[b,s,i] * (W[o,i] + sum_r A[o,r]*B[r,i]) + bias[o]
// M = 16384, N = 4096, K = 4096. fp32 in/out, bf16 MFMA compute.
// GEMM: 256x256 tile, BK=64, 8 waves, 8-phase, 16x16x32 MFMA.
// R14 = R10 + barriers/vmcnt ONLY at even phases (4 sync points per 2
//   K-tiles instead of 8). Wave skew across odd phases overlaps one wave's
//   LDS drain with another's MFMA. Hazard proofs: stage->read distance 5-6
//   with vmcnt(4)@even proving stages <= p-3 cross-wave; every restage has
//   an even barrier between old-content retire (lgkmcnt(0)) and stage issue
//   (even-phase stages AFTER the barrier, odd covered by preceding barrier).

#define MDIM 16384
#define NDIM 4096
#define KDIM 4096
#define RANK 16
#define NT   (KDIM / 64)   // 64 K-tiles

typedef __bf16  bf16x8 __attribute__((ext_vector_type(8)));
typedef float   f32x4  __attribute__((ext_vector_type(4)));
typedef unsigned short u16x8 __attribute__((ext_vector_type(8)));

__device__ __forceinline__ unsigned short f2bf(float f) {
  union { float f; uint32_t u; } v; v.f = f;
  uint32_t r = v.u + 0x7FFFu + ((v.u >> 16) & 1u);
  return (unsigned short)(r >> 16);
}

__device__ __forceinline__ void gl16(const void* g, void* l) {
  __builtin_amdgcn_global_load_lds(
      (__attribute__((address_space(1))) void*)(g),
      (__attribute__((address_space(3))) void*)(l),
      16, 0, 0);
}

// Fused prep: blocks [0, 32768) cast x fp32->bf16 (8 elems/thread);
//             blocks [32768, 40960) compute Wp = bf16(W + A@B).
#define CAST_BLOCKS 32768
__global__ void prep_fused(const float* __restrict__ x,
                           const float* __restrict__ W,
                           const float* __restrict__ A,
                           const float* __restrict__ Bm,
                           unsigned short* __restrict__ xb,
                           unsigned short* __restrict__ Wp) {
  const int b = blockIdx.x;
  if (b < CAST_BLOCKS) {
    const size_t i = ((size_t)b * 256 + threadIdx.x) * 8;
    float4 a0 = *(const float4*)(x + i);
    float4 a1 = *(const float4*)(x + i + 4);
    u16x8 o;
    o[0] = f2bf(a0.x); o[1] = f2bf(a0.y); o[2] = f2bf(a0.z); o[3] = f2bf(a0.w);
    o[4] = f2bf(a1.x); o[5] = f2bf(a1.y); o[6] = f2bf(a1.z); o[7] = f2bf(a1.w);
    *(u16x8*)(xb + i) = o;
  } else {
    const size_t idx = ((size_t)(b - CAST_BLOCKS) * 256 + threadIdx.x) * 8;
    const int o  = (int)(idx >> 12);
    const int i0 = (int)(idx & 4095);
    float accv[8];
    {
      float4 w0 = *(const float4*)(W + (size_t)o * NDIM + i0);
      float4 w1 = *(const float4*)(W + (size_t)o * NDIM + i0 + 4);
      accv[0] = w0.x; accv[1] = w0.y; accv[2] = w0.z; accv[3] = w0.w;
      accv[4] = w1.x; accv[5] = w1.y; accv[6] = w1.z; accv[7] = w1.w;
    }
#pragma unroll
    for (int r = 0; r < RANK; ++r) {
      const float ar = A[o * RANK + r];
      float4 b0 = *(const float4*)(Bm + (size_t)r * NDIM + i0);
      float4 b1 = *(const float4*)(Bm + (size_t)r * NDIM + i0 + 4);
      accv[0] += ar * b0.x; accv[1] += ar * b0.y;
      accv[2] += ar * b0.z; accv[3] += ar * b0.w;
      accv[4] += ar * b1.x; accv[5] += ar * b1.y;
      accv[6] += ar * b1.z; accv[7] += ar * b1.w;
    }
    u16x8 ov;
#pragma unroll
    for (int j = 0; j < 8; ++j) ov[j] = f2bf(accv[j]);
    *(u16x8*)(Wp + idx) = ov;
  }
}

#define BARRIER  __builtin_amdgcn_s_barrier()
#define VMCNT8   asm volatile("s_waitcnt vmcnt(8)" ::: "memory")
#define VMCNT4   asm volatile("s_waitcnt vmcnt(4)" ::: "memory")
#define WAITVM0  asm volatile("s_waitcnt vmcnt(0)" ::: "memory")
#define LGKMC_(n) asm volatile("s_waitcnt lgkmcnt(" #n ")" ::: "memory")
#define LGKMC(n) LGKMC_(n)
#define SCHEDB   __builtin_amdgcn_sched_barrier(0)
#define PRIO1    __builtin_amdgcn_s_setprio(1)
#define PRIO0    __builtin_amdgcn_s_setprio(0)

// inline-asm LDS read, compile-time byte offset immediate
#define DSR(dst, addr, imm)                                                   \
  asm volatile("ds_read_b128 %0, %1 offset:%c2"                               \
               : "=v"(dst) : "v"(addr), "n"(imm) : "memory")

// ---- staging: one half-tile = 2 x gl16 per thread ----
#define STAGE_A(buf, h, kt) do {                                              \
    const int kc_ = ((kt) < NT ? (kt) : NT - 1);                              \
    const unsigned short* g_ = agb + (size_t)((h) * 64) * KDIM + kc_ * 64;    \
    unsigned short* d_ = &sA[(buf)][0] + (h) * 8192 + t * 8;                  \
    gl16(g_, d_);                                                             \
    gl16(g_ + (size_t)128 * KDIM, d_ + 4096);                                 \
  } while (0)

#define STAGE_B(buf, h, kt) do {                                              \
    const int kc_ = ((kt) < NT ? (kt) : NT - 1);                              \
    const unsigned short* g_ = bgb + (size_t)((h) * 32) * KDIM + kc_ * 64;    \
    unsigned short* d_ = &sB[(buf)][0] + (h) * 8192 + t * 8;                  \
    gl16(g_, d_);                                                             \
    gl16(g_ + (size_t)128 * KDIM, d_ + 4096);                                 \
  } while (0)

// A fragments, issued mi-major (consumption order for mi clusters).
#define LDA(buf, mh) do {                                                     \
    DSR(a[0][0], aAddr0, (buf)*32768 + (mh)*16384 + 0);                       \
    DSR(a[0][1], aAddr1, (buf)*32768 + (mh)*16384 + 0);                       \
    DSR(a[1][0], aAddr0, (buf)*32768 + (mh)*16384 + 2048);                    \
    DSR(a[1][1], aAddr1, (buf)*32768 + (mh)*16384 + 2048);                    \
    DSR(a[2][0], aAddr0, (buf)*32768 + (mh)*16384 + 4096);                    \
    DSR(a[2][1], aAddr1, (buf)*32768 + (mh)*16384 + 4096);                    \
    DSR(a[3][0], aAddr0, (buf)*32768 + (mh)*16384 + 6144);                    \
    DSR(a[3][1], aAddr1, (buf)*32768 + (mh)*16384 + 6144);                    \
  } while (0)

// B fragments, ni-major.
#define LDB(bb, buf, nh) do {                                                 \
    DSR(bb[0][0], bAddr0, (buf)*32768 + (nh)*16384 + 0);                      \
    DSR(bb[0][1], bAddr1, (buf)*32768 + (nh)*16384 + 0);                      \
    DSR(bb[1][0], bAddr0, (buf)*32768 + (nh)*16384 + 2048);                   \
    DSR(bb[1][1], bAddr1, (buf)*32768 + (nh)*16384 + 2048);                   \
  } while (0)

// MFMA clusters
#define MMmi(mh, nh, mi, bb) do {                                             \
    _Pragma("unroll") for (int ni = 0; ni < 2; ++ni)                          \
    _Pragma("unroll") for (int kk = 0; kk < 2; ++kk)                          \
      acc[(mh)*4+(mi)][(nh)*2+ni] = __builtin_amdgcn_mfma_f32_16x16x32_bf16(  \
          a[mi][kk], bb[ni][kk], acc[(mh)*4+(mi)][(nh)*2+ni], 0, 0, 0);       \
  } while (0)

#define MMni(mh, nh, ni, bb) do {                                             \
    _Pragma("unroll") for (int mi = 0; mi < 4; ++mi)                          \
    _Pragma("unroll") for (int kk = 0; kk < 2; ++kk)                          \
      acc[(mh)*4+mi][(nh)*2+(ni)] = __builtin_amdgcn_mfma_f32_16x16x32_bf16(  \
          a[mi][kk], bb[ni][kk], acc[(mh)*4+mi][(nh)*2+(ni)], 0, 0, 0);       \
  } while (0)

#define MMfull(mh, nh, bb) do {                                               \
    _Pragma("unroll") for (int mi = 0; mi < 4; ++mi)                          \
    _Pragma("unroll") for (int ni = 0; ni < 2; ++ni)                          \
    _Pragma("unroll") for (int kk = 0; kk < 2; ++kk)                          \
      acc[(mh)*4+mi][(nh)*2+ni] = __builtin_amdgcn_mfma_f32_16x16x32_bf16(    \
          a[mi][kk], bb[ni][kk], acc[(mh)*4+mi][(nh)*2+ni], 0, 0, 0);         \
  } while (0)

// A-read phase: 8 a-reads in flight (+possibly 4 earlier b); 4 mi-clusters.
#define PH_A(bb, mh, nh)                                                      \
    PRIO1; LGKMC(6); SCHEDB; MMmi(mh, nh, 0, bb);                             \
    LGKMC(4); SCHEDB; MMmi(mh, nh, 1, bb);                                    \
    LGKMC(2); SCHEDB; MMmi(mh, nh, 2, bb);                                    \
    LGKMC(0); SCHEDB; MMmi(mh, nh, 3, bb); PRIO0

// B-read phase: 4 b-reads in flight; 2 ni-clusters.
#define PH_B(bb, mh, nh)                                                      \
    PRIO1; LGKMC(2); SCHEDB; MMni(mh, nh, 0, bb);                             \
    LGKMC(0); SCHEDB; MMni(mh, nh, 1, bb); PRIO0

__global__ __launch_bounds__(512, 2) void gemm256(
    const unsigned short* __restrict__ Xb,
    const unsigned short* __restrict__ Wp,
    const float* __restrict__ bias,
    float* __restrict__ out) {
  __shared__ __align__(16) unsigned short sA[2][256 * 64];  // 64 KiB
  __shared__ __align__(16) unsigned short sB[2][256 * 64];  // 64 KiB

  const int t  = threadIdx.x;
  const int l  = t & 63;
  const int w  = t >> 6;   // 0..7
  const int wm = w >> 2;   // 0..1  (m half: 128 rows)
  const int wn = w & 3;    // 0..3  (n quarter: 64 cols)

  // XCD-aware bijective swizzle; n-fastest: each XCD owns an 8-row bm band.
  const int bid = blockIdx.x;
  const int swz = (bid & 7) * (1024 / 8) + (bid >> 3);
  const int bm  = (swz >> 4) * 256;   // 64 m-tiles
  const int bn  = (swz & 15) * 256;   // 16 n-tiles

  // ---- staging bases ----
  const int sr  = t >> 3;  // LDS-row-within-half 0..63
  const int ske = (((t & 7) * 16) ^ ((sr & 7) << 4)) >> 1;  // bytes -> elems
  const unsigned short* agb = Xb + (size_t)(bm + sr) * KDIM + ske;
  const unsigned short* bgb = Wp + (size_t)(bn + (sr >> 5) * 64 + (sr & 31)) * KDIM + ske;

  // ---- ds_read address registers (loop-invariant) ----
  const int lr   = l & 15;
  const int koff = (l >> 4) * 8;      // elements
  const int xorE = (lr & 7) << 3;     // elements ((row&7)<<4 bytes)
  const unsigned ldsA = (unsigned)(uintptr_t)&sA[0][0];
  const unsigned ldsB = (unsigned)(uintptr_t)&sB[0][0];
  const unsigned aAddr0 = ldsA + (unsigned)((wm * 64 + lr) * 128 + ((koff ^ xorE) * 2));
  const unsigned aAddr1 = ldsA + (unsigned)((wm * 64 + lr) * 128 + (((32 + koff) ^ xorE) * 2));
  const unsigned bAddr0 = ldsB + (unsigned)((wn * 32 + lr) * 128 + ((koff ^ xorE) * 2));
  const unsigned bAddr1 = ldsB + (unsigned)((wn * 32 + lr) * 128 + (((32 + koff) ^ xorE) * 2));

  bf16x8 a[4][2], b0[2][2], b1[2][2];
  f32x4 acc[8][4];
#pragma unroll
  for (int i = 0; i < 8; ++i)
#pragma unroll
    for (int j = 0; j < 4; ++j)
      acc[i][j] = f32x4{0.f, 0.f, 0.f, 0.f};

  // ---- prologue: 8 half-tiles (all of buf0/t0 + all of buf1/t1);
  //      vmcnt(8) proves buf0 fully landed; barrier broadcasts.
  //      (it=0's P0/P1 re-stage B1h1/A1h1 with identical data — benign.)
  STAGE_B(0, 0, 0); STAGE_A(0, 0, 0);
  STAGE_B(0, 1, 0); STAGE_A(0, 1, 0);
  STAGE_B(1, 0, 1); STAGE_A(1, 0, 1);
  STAGE_B(1, 1, 1); STAGE_A(1, 1, 1);
  VMCNT8;
  BARRIER;

  // ---- main loop: 2 K-tiles / iter, 8 phases, sync only at even phases.
  // even p: [reads][VMCNT4][BARRIER][STAGE][MFMA]
  // odd  p: [reads][STAGE][MFMA]            (no barrier, no vmcnt)
  for (int it = 0; it < NT / 2; ++it) {
    const int E = it * 2;
    // P0: q00 buf0
    LDB(b0, 0, 0); LDA(0, 0);
    VMCNT4; BARRIER;
    STAGE_B(1, 1, E + 1);
    PH_A(b0, 0, 0);
    // P1: q01 buf0
    LDB(b1, 0, 1);
    STAGE_A(1, 1, E + 1);
    PH_B(b1, 0, 1);
    // P2: q11 buf0
    LDA(0, 1);
    VMCNT4; BARRIER;
    STAGE_B(0, 0, E + 2);
    PH_A(b1, 1, 1);
    // P3: q10 buf0 (register-only MFMA)
    STAGE_A(0, 0, E + 2);
    PRIO1; MMfull(1, 0, b0); PRIO0;
    // P4: q00 buf1
    LDB(b0, 1, 0); LDA(1, 0);
    VMCNT4; BARRIER;
    STAGE_B(0, 1, E + 2);
    PH_A(b0, 0, 0);
    // P5: q01 buf1
    LDB(b1, 1, 1);
    STAGE_A(0, 1, E + 2);
    PH_B(b1, 0, 1);
    // P6: q11 buf1
    LDA(1, 1);
    VMCNT4; BARRIER;
    STAGE_B(1, 0, E + 3);
    PH_A(b1, 1, 1);
    // P7: q10 buf1 (register-only MFMA)
    STAGE_A(1, 0, E + 3);
    PRIO1; MMfull(1, 0, b0); PRIO0;
  }

  LGKMC(0);  // retire any trailing ds ops
  WAITVM0;   // drain stray (clamped) prefetches before exit

  // ---- epilogue: C/D layout col=lane&15, row=(lane>>4)*4+reg ----
#pragma unroll
  for (int mf = 0; mf < 8; ++mf) {
#pragma unroll
    for (int nf = 0; nf < 4; ++nf) {
      const int row = bm + wm * 128 + mf * 16 + (l >> 4) * 4;
      const int col = bn + wn * 64 + nf * 16 + lr;
      const float bv = bias[col];
#pragma unroll
      for (int r = 0; r < 4; ++r)
        out[(size_t)(row + r) * NDIM + col] = acc[mf][nf][r] + bv;
    }
  }
}

extern "C" void kernel_launch(void* const* d_in, const int* in_sizes, int n_in,
                              void* d_out, int out_size, void* d_ws, size_t ws_size,
                              hipStream_t stream) {
  const float* x    = (const float*)d_in[0];
  const float* W    = (const float*)d_in[1];
  const float* bias = (const float*)d_in[2];
  const float* A    = (const float*)d_in[3];
  const float* B    = (const float*)d_in[4];
  float* out        = (float*)d_out;

  unsigned short* Wp = (unsigned short*)d_ws;                       // 32 MiB
  unsigned short* Xb = (unsigned short*)d_ws + (size_t)NDIM * KDIM; // 128 MiB

  prep_fused<<<dim3(CAST_BLOCKS + 8192), 256, 0, stream>>>(x, W, A, B, Xb, Wp);
  gemm256<<<dim3((MDIM / 256) * (NDIM / 256)), 512, 0, stream>>>(Xb, Wp, bias, out);
}

// Round 16
// 576.602 us; speedup vs baseline: 1.0128x; 1.0128x over previous
//
#include <hip/hip_runtime.h>
#include <stdint.h>

// out[b,s,o] = sum_i x[b,s,i] * (W[o,i] + sum_r A[o,r]*B[r,i]) + bias[o]
// M = 16384, N = 4096, K = 4096. fp32 in/out, bf16 MFMA compute.
// GEMM: 256x256 tile, BK=64, 8 waves, 8-phase, ONE barrier/phase, 16x16x32.
// R16 = R13 (measured best: gemm 448us, MfmaUtil 58.9%) + native bf16 casts
//   in prep (compiler emits v_cvt_pk_bf16_f32). R15's prep-fold reverted:
//   async-reg staging across the loop back-edge is unprotectable against
//   regalloc copies (compiler-invisible VMEM dest regs).

#define MDIM 16384
#define NDIM 4096
#define KDIM 4096
#define RANK 16
#define NT   (KDIM / 64)   // 64 K-tiles

typedef __bf16  bf16x8 __attribute__((ext_vector_type(8)));
typedef float   f32x4  __attribute__((ext_vector_type(4)));
typedef __bf16  bf16x4 __attribute__((ext_vector_type(4)));

__device__ __forceinline__ void gl16(const void* g, void* l) {
  __builtin_amdgcn_global_load_lds(
      (__attribute__((address_space(1))) void*)(g),
      (__attribute__((address_space(3))) void*)(l),
      16, 0, 0);
}

// Fused prep: blocks [0, 32768) cast x fp32->bf16 (8 elems/thread);
//             blocks [32768, 40960) compute Wp = bf16(W + A@B).
#define CAST_BLOCKS 32768
__global__ void prep_fused(const float* __restrict__ x,
                           const float* __restrict__ W,
                           const float* __restrict__ A,
                           const float* __restrict__ Bm,
                           __bf16* __restrict__ xb,
                           __bf16* __restrict__ Wp) {
  const int b = blockIdx.x;
  if (b < CAST_BLOCKS) {
    const size_t i = ((size_t)b * 256 + threadIdx.x) * 8;
    float4 a0 = *(const float4*)(x + i);
    float4 a1 = *(const float4*)(x + i + 4);
    bf16x8 o;
    o[0] = (__bf16)a0.x; o[1] = (__bf16)a0.y; o[2] = (__bf16)a0.z; o[3] = (__bf16)a0.w;
    o[4] = (__bf16)a1.x; o[5] = (__bf16)a1.y; o[6] = (__bf16)a1.z; o[7] = (__bf16)a1.w;
    *(bf16x8*)(xb + i) = o;
  } else {
    const size_t idx = ((size_t)(b - CAST_BLOCKS) * 256 + threadIdx.x) * 8;
    const int o  = (int)(idx >> 12);
    const int i0 = (int)(idx & 4095);
    float accv[8];
    {
      float4 w0 = *(const float4*)(W + (size_t)o * NDIM + i0);
      float4 w1 = *(const float4*)(W + (size_t)o * NDIM + i0 + 4);
      accv[0] = w0.x; accv[1] = w0.y; accv[2] = w0.z; accv[3] = w0.w;
      accv[4] = w1.x; accv[5] = w1.y; accv[6] = w1.z; accv[7] = w1.w;
    }
#pragma unroll
    for (int r = 0; r < RANK; ++r) {
      const float ar = A[o * RANK + r];
      float4 b0 = *(const float4*)(Bm + (size_t)r * NDIM + i0);
      float4 b1 = *(const float4*)(Bm + (size_t)r * NDIM + i0 + 4);
      accv[0] += ar * b0.x; accv[1] += ar * b0.y;
      accv[2] += ar * b0.z; accv[3] += ar * b0.w;
      accv[4] += ar * b1.x; accv[5] += ar * b1.y;
      accv[6] += ar * b1.z; accv[7] += ar * b1.w;
    }
    bf16x8 ov;
#pragma unroll
    for (int j = 0; j < 8; ++j) ov[j] = (__bf16)accv[j];
    *(bf16x8*)(Wp + idx) = ov;
  }
}

#define BARRIER  __builtin_amdgcn_s_barrier()
#define VMCNT8   asm volatile("s_waitcnt vmcnt(8)" ::: "memory")
#define WAITVM0  asm volatile("s_waitcnt vmcnt(0)" ::: "memory")
#define LGKMC_(n) asm volatile("s_waitcnt lgkmcnt(" #n ")" ::: "memory")
#define LGKMC(n) LGKMC_(n)
#define SCHEDB   __builtin_amdgcn_sched_barrier(0)
#define PRIO1    __builtin_amdgcn_s_setprio(1)
#define PRIO0    __builtin_amdgcn_s_setprio(0)

// inline-asm LDS read, compile-time byte offset immediate
#define DSR(dst, addr, imm)                                                   \
  asm volatile("ds_read_b128 %0, %1 offset:%c2"                               \
               : "=v"(dst) : "v"(addr), "n"(imm) : "memory")

// ---- staging: one half-tile = 2 x gl16 per thread ----
#define STAGE_A(buf, h, kt) do {                                              \
    const int kc_ = ((kt) < NT ? (kt) : NT - 1);                              \
    const __bf16* g_ = agb + (size_t)((h) * 64) * KDIM + kc_ * 64;            \
    __bf16* d_ = &sA[(buf)][0] + (h) * 8192 + t * 8;                          \
    gl16(g_, d_);                                                             \
    gl16(g_ + (size_t)128 * KDIM, d_ + 4096);                                 \
  } while (0)

#define STAGE_B(buf, h, kt) do {                                              \
    const int kc_ = ((kt) < NT ? (kt) : NT - 1);                              \
    const __bf16* g_ = bgb + (size_t)((h) * 32) * KDIM + kc_ * 64;            \
    __bf16* d_ = &sB[(buf)][0] + (h) * 8192 + t * 8;                          \
    gl16(g_, d_);                                                             \
    gl16(g_ + (size_t)128 * KDIM, d_ + 4096);                                 \
  } while (0)

// A fragments, issued mi-major (consumption order for mi clusters).
#define LDA(buf, mh) do {                                                     \
    DSR(a[0][0], aAddr0, (buf)*32768 + (mh)*16384 + 0);                       \
    DSR(a[0][1], aAddr1, (buf)*32768 + (mh)*16384 + 0);                       \
    DSR(a[1][0], aAddr0, (buf)*32768 + (mh)*16384 + 2048);                    \
    DSR(a[1][1], aAddr1, (buf)*32768 + (mh)*16384 + 2048);                    \
    DSR(a[2][0], aAddr0, (buf)*32768 + (mh)*16384 + 4096);                    \
    DSR(a[2][1], aAddr1, (buf)*32768 + (mh)*16384 + 4096);                    \
    DSR(a[3][0], aAddr0, (buf)*32768 + (mh)*16384 + 6144);                    \
    DSR(a[3][1], aAddr1, (buf)*32768 + (mh)*16384 + 6144);                    \
  } while (0)

// B fragments, ni-major.
#define LDB(bb, buf, nh) do {                                                 \
    DSR(bb[0][0], bAddr0, (buf)*32768 + (nh)*16384 + 0);                      \
    DSR(bb[0][1], bAddr1, (buf)*32768 + (nh)*16384 + 0);                      \
    DSR(bb[1][0], bAddr0, (buf)*32768 + (nh)*16384 + 2048);                   \
    DSR(bb[1][1], bAddr1, (buf)*32768 + (nh)*16384 + 2048);                   \
  } while (0)

// MFMA clusters
#define MMmi(mh, nh, mi, bb) do {                                             \
    _Pragma("unroll") for (int ni = 0; ni < 2; ++ni)                          \
    _Pragma("unroll") for (int kk = 0; kk < 2; ++kk)                          \
      acc[(mh)*4+(mi)][(nh)*2+ni] = __builtin_amdgcn_mfma_f32_16x16x32_bf16(  \
          a[mi][kk], bb[ni][kk], acc[(mh)*4+(mi)][(nh)*2+ni], 0, 0, 0);       \
  } while (0)

#define MMni(mh, nh, ni, bb) do {                                             \
    _Pragma("unroll") for (int mi = 0; mi < 4; ++mi)                          \
    _Pragma("unroll") for (int kk = 0; kk < 2; ++kk)                          \
      acc[(mh)*4+mi][(nh)*2+(ni)] = __builtin_amdgcn_mfma_f32_16x16x32_bf16(  \
          a[mi][kk], bb[ni][kk], acc[(mh)*4+mi][(nh)*2+(ni)], 0, 0, 0);       \
  } while (0)

#define MMfull(mh, nh, bb) do {                                               \
    _Pragma("unroll") for (int mi = 0; mi < 4; ++mi)                          \
    _Pragma("unroll") for (int ni = 0; ni < 2; ++ni)                          \
    _Pragma("unroll") for (int kk = 0; kk < 2; ++kk)                          \
      acc[(mh)*4+mi][(nh)*2+ni] = __builtin_amdgcn_mfma_f32_16x16x32_bf16(    \
          a[mi][kk], bb[ni][kk], acc[(mh)*4+mi][(nh)*2+ni], 0, 0, 0);         \
  } while (0)

// A-read phase: 8 a-reads in flight (+earlier 4 b); 4 mi-clusters.
#define PH_A(bb, mh, nh)                                                      \
    PRIO1; LGKMC(6); SCHEDB; MMmi(mh, nh, 0, bb);                             \
    LGKMC(4); SCHEDB; MMmi(mh, nh, 1, bb);                                    \
    LGKMC(2); SCHEDB; MMmi(mh, nh, 2, bb);                                    \
    LGKMC(0); SCHEDB; MMmi(mh, nh, 3, bb); PRIO0

// B-read phase: 4 b-reads in flight; 2 ni-clusters.
#define PH_B(bb, mh, nh)                                                      \
    PRIO1; LGKMC(2); SCHEDB; MMni(mh, nh, 0, bb);                             \
    LGKMC(0); SCHEDB; MMni(mh, nh, 1, bb); PRIO0

__global__ __launch_bounds__(512, 2) void gemm256(
    const __bf16* __restrict__ Xb,
    const __bf16* __restrict__ Wp,
    const float* __restrict__ bias,
    float* __restrict__ out) {
  __shared__ __align__(16) __bf16 sA[2][256 * 64];  // 64 KiB
  __shared__ __align__(16) __bf16 sB[2][256 * 64];  // 64 KiB

  const int t  = threadIdx.x;
  const int l  = t & 63;
  const int w  = t >> 6;   // 0..7
  const int wm = w >> 2;   // 0..1  (m half: 128 rows)
  const int wn = w & 3;    // 0..3  (n quarter: 64 cols)

  // XCD-aware bijective swizzle; n-fastest: each XCD owns an 8-row bm band.
  const int bid = blockIdx.x;
  const int swz = (bid & 7) * (1024 / 8) + (bid >> 3);
  const int bm  = (swz >> 4) * 256;   // 64 m-tiles
  const int bn  = (swz & 15) * 256;   // 16 n-tiles

  // ---- staging bases ----
  const int sr  = t >> 3;  // LDS-row-within-half 0..63
  const int ske = (((t & 7) * 16) ^ ((sr & 7) << 4)) >> 1;  // bytes -> elems
  const __bf16* agb = Xb + (size_t)(bm + sr) * KDIM + ske;
  const __bf16* bgb = Wp + (size_t)(bn + (sr >> 5) * 64 + (sr & 31)) * KDIM + ske;

  // ---- ds_read address registers (loop-invariant) ----
  const int lr   = l & 15;
  const int koff = (l >> 4) * 8;      // elements
  const int xorE = (lr & 7) << 3;     // elements ((row&7)<<4 bytes)
  const unsigned ldsA = (unsigned)(uintptr_t)&sA[0][0];
  const unsigned ldsB = (unsigned)(uintptr_t)&sB[0][0];
  const unsigned aAddr0 = ldsA + (unsigned)((wm * 64 + lr) * 128 + ((koff ^ xorE) * 2));
  const unsigned aAddr1 = ldsA + (unsigned)((wm * 64 + lr) * 128 + (((32 + koff) ^ xorE) * 2));
  const unsigned bAddr0 = ldsB + (unsigned)((wn * 32 + lr) * 128 + ((koff ^ xorE) * 2));
  const unsigned bAddr1 = ldsB + (unsigned)((wn * 32 + lr) * 128 + (((32 + koff) ^ xorE) * 2));

  bf16x8 a[4][2], b0[2][2], b1[2][2];
  f32x4 acc[8][4];
#pragma unroll
  for (int i = 0; i < 8; ++i)
#pragma unroll
    for (int j = 0; j < 4; ++j)
      acc[i][j] = f32x4{0.f, 0.f, 0.f, 0.f};

  // ---- prologue: 6 half-tiles in consumption order; vmcnt(8) proves the
  //      first two (B0b0, A0b0) landed; barrier broadcasts.
  STAGE_B(0, 0, 0); STAGE_A(0, 0, 0);
  STAGE_B(0, 1, 0); STAGE_A(0, 1, 0);
  STAGE_B(1, 0, 1); STAGE_A(1, 0, 1);
  VMCNT8;
  BARRIER;

  // ---- main loop: 2 K-tiles / iter, 8 phases, ONE barrier per phase.
  // Phase p: [reads_p (consume stage_{p-5/p-6})] [STAGE 1 half] [vmcnt(8)]
  //          [barrier] [MFMA with counted-lgkm clusters].
  for (int it = 0; it < NT / 2; ++it) {
    const int E = it * 2;
    // P0: q00 buf0  [reads: B0b0 x4 + A0b0 x8]
    LDB(b0, 0, 0); LDA(0, 0);
    STAGE_B(1, 1, E + 1);
    VMCNT8; BARRIER;
    PH_A(b0, 0, 0);
    // P1: q01 buf0  [reads: B1b0 x4]
    LDB(b1, 0, 1);
    STAGE_A(1, 1, E + 1);
    VMCNT8; BARRIER;
    PH_B(b1, 0, 1);
    // P2: q11 buf0  [reads: A1b0 x8]
    LDA(0, 1);
    STAGE_B(0, 0, E + 2);
    VMCNT8; BARRIER;
    PH_A(b1, 1, 1);
    // P3: q10 buf0  [no reads]
    STAGE_A(0, 0, E + 2);
    VMCNT8; BARRIER;
    PRIO1; MMfull(1, 0, b0); PRIO0;
    // P4: q00 buf1  [reads: B0b1 x4 + A0b1 x8]
    LDB(b0, 1, 0); LDA(1, 0);
    STAGE_B(0, 1, E + 2);
    VMCNT8; BARRIER;
    PH_A(b0, 0, 0);
    // P5: q01 buf1  [reads: B1b1 x4]
    LDB(b1, 1, 1);
    STAGE_A(0, 1, E + 2);
    VMCNT8; BARRIER;
    PH_B(b1, 0, 1);
    // P6: q11 buf1  [reads: A1b1 x8]
    LDA(1, 1);
    STAGE_B(1, 0, E + 3);
    VMCNT8; BARRIER;
    PH_A(b1, 1, 1);
    // P7: q10 buf1  [no reads]
    STAGE_A(1, 0, E + 3);
    VMCNT8; BARRIER;
    PRIO1; MMfull(1, 0, b0); PRIO0;
  }

  LGKMC(0);  // retire any trailing ds ops
  WAITVM0;   // drain stray (clamped) prefetches before exit

  // ---- epilogue: C/D layout col=lane&15, row=(lane>>4)*4+reg ----
#pragma unroll
  for (int mf = 0; mf < 8; ++mf) {
#pragma unroll
    for (int nf = 0; nf < 4; ++nf) {
      const int row = bm + wm * 128 + mf * 16 + (l >> 4) * 4;
      const int col = bn + wn * 64 + nf * 16 + lr;
      const float bv = bias[col];
#pragma unroll
      for (int r = 0; r < 4; ++r)
        out[(size_t)(row + r) * NDIM + col] = acc[mf][nf][r] + bv;
    }
  }
}

extern "C" void kernel_launch(void* const* d_in, const int* in_sizes, int n_in,
                              void* d_out, int out_size, void* d_ws, size_t ws_size,
                              hipStream_t stream) {
  const float* x    = (const float*)d_in[0];
  const float* W    = (const float*)d_in[1];
  const float* bias = (const float*)d_in[2];
  const float* A    = (const float*)d_in[3];
  const float* B    = (const float*)d_in[4];
  float* out        = (float*)d_out;

  __bf16* Wp = (__bf16*)d_ws;                       // 32 MiB
  __bf16* Xb = (__bf16*)d_ws + (size_t)NDIM * KDIM; // 128 MiB

  prep_fused<<<dim3(CAST_BLOCKS + 8192), 256, 0, stream>>>(x, W, A, B, Xb, Wp);
  gemm256<<<dim3((MDIM / 256) * (NDIM / 256)), 512, 0, stream>>>(Xb, Wp, bias, out);
}